// Round 4
// baseline (296.592 us; speedup 1.0000x reference)
//
#include <hip/hip_runtime.h>

typedef float f32x4 __attribute__((ext_vector_type(4)));
typedef short bf16x8 __attribute__((ext_vector_type(8)));

// ---- workspace layout (bytes) ----
// B1s: [16 kb][528 cols][128 B]  (bf16, chunk-swizzled; cols 512-519 router, 520-527 zero)
// W2s: [1024 cols][640 B]        (bf16, chunk-swizzled; rows 256-263 = b2, 264-319 zero)
// ACT: [32768 rows][640 B]       (bf16, chunk-swizzled; k 256-263 = p, 264-319 zero)
#define B1S_KBSZ 67584
#define W2S_OFF  1081344
#define ACT_OFF  1736704
// total ws required: 22,708,224 bytes

__device__ __forceinline__ unsigned short f2bf(float f) {
  unsigned int u = __float_as_uint(f);
  return (unsigned short)((u + 0x7FFFu + ((u >> 16) & 1u)) >> 16);
}
__device__ __forceinline__ unsigned int pack2(float a, float b) {
  return (unsigned int)f2bf(a) | ((unsigned int)f2bf(b) << 16);
}
__device__ __forceinline__ unsigned int cvtpk(float a, float b) {
  unsigned int r;
  asm("v_cvt_pk_bf16_f32 %0, %1, %2" : "=v"(r) : "v"(a), "v"(b));
  return r;
}
__device__ __forceinline__ void async16(const void* g, void* l) {
  __builtin_amdgcn_global_load_lds(
      (const __attribute__((address_space(1))) unsigned int*)g,
      (__attribute__((address_space(3))) unsigned int*)l, 16, 0, 0);
}

// ---------------- prep: pack [W1|Wr|0] -> B1s ; [W2;b2;0] -> W2s ----------------
__global__ __launch_bounds__(256) void prep_all(const float* __restrict__ W1,
                                                const float* __restrict__ Wr,
                                                const float* __restrict__ W2,
                                                const float* __restrict__ b2,
                                                unsigned char* __restrict__ B1s,
                                                unsigned char* __restrict__ W2s) {
  if (blockIdx.x < 33) {
    int t = blockIdx.x * 256 + threadIdx.x;
    if (t >= 528 * 16) return;
    int col = t % 528;
    int kb  = t / 528;
    unsigned char* dst = B1s + kb * B1S_KBSZ + col * 128;
    int key = col & 7;
    int e   = col >> 6;
    int hh  = col & 63;
    #pragma unroll
    for (int c = 0; c < 8; ++c) {
      float v[8];
      #pragma unroll
      for (int jj = 0; jj < 8; ++jj) {
        int k = kb * 64 + c * 8 + jj;
        float f;
        if (col < 512)      f = W1[(e * 1024 + k) * 64 + hh];   // W1[e][k][hh]
        else if (col < 520) f = Wr[k * 8 + (col - 512)];        // Wr[k][e]
        else                f = 0.0f;
        v[jj] = f;
      }
      *(uint4*)(dst + ((c ^ key) * 16)) =
          make_uint4(pack2(v[0], v[1]), pack2(v[2], v[3]), pack2(v[4], v[5]), pack2(v[6], v[7]));
    }
  } else {
    int c = (blockIdx.x - 33) * 256 + threadIdx.x;
    if (c >= 1024) return;
    unsigned char* dst = W2s + c * 640;
    int key = c & 7;
    #pragma unroll 1
    for (int cj = 0; cj < 40; ++cj) {
      float v[8];
      #pragma unroll
      for (int jj = 0; jj < 8; ++jj) {
        int k = cj * 8 + jj;
        float f;
        if (k < 256)      f = W2[k * 1024 + c];          // W2[e][h][c], k=e*32+h
        else if (k < 264) f = b2[(k - 256) * 1024 + c];  // b2[e][c]
        else              f = 0.0f;
        v[jj] = f;
      }
      int dstc = (cj & ~7) | ((cj & 7) ^ key);
      *(uint4*)(dst + dstc * 16) =
          make_uint4(pack2(v[0], v[1]), pack2(v[2], v[3]), pack2(v[4], v[5]), pack2(v[6], v[7]));
    }
  }
}

// ---------------- kernel 1: 128 rows x 272 cols (expert-quad), single-buffer 2-barrier ----------------
// grid 512 = 256 M-tiles x 2 quads; block 512 = 8 waves (2 mg x 4 ng), wave 64x80/64
__global__ __launch_bounds__(512, 4) void moe_gemm1(
    const float* __restrict__ x, const float* __restrict__ br, const float* __restrict__ b1,
    const unsigned char* __restrict__ B1s, unsigned char* __restrict__ ACT) {
  __shared__ __align__(16) unsigned char smem[51200];
  // K-loop: B [0, 34816) = 17 col-frags x 2048 ; A [34816, 51200) = 128 rows x 128 B
  // epilogue aliases: hb u16[128][136] @ 0 ; logit f32[128][8] @ 34816 ; pb u16[128][8] @ 38912

  const int tid  = threadIdx.x;
  const int lane = tid & 63;
  const int w    = tid >> 6;
  const int mg   = w >> 2;   // rows mg*64 .. +64
  const int ng   = w & 3;    // expert frags ng*4 .. +4 ; ng==0 also router (frag 16)
  const int f15  = lane & 15;
  const int fhi  = lane >> 4;

  const int wid   = ((blockIdx.x & 7) << 6) + (blockIdx.x >> 3);  // XCD-chunked, 512=8*64
  const int mtile = wid >> 1;
  const int p     = wid & 1;   // expert quad: experts p*4 .. p*4+3
  const int m0    = mtile << 7;

  f32x4 acc[4][5];
  #pragma unroll
  for (int a = 0; a < 4; ++a)
    #pragma unroll
    for (int b = 0; b < 5; ++b) acc[a][b] = f32x4{0.f, 0.f, 0.f, 0.f};

  // A staging: thread = (row tid>>2, 16-float chunk tid&3)
  const int srow = tid >> 2;
  const int scg  = tid & 3;
  const float* xrow = x + (size_t)(m0 + srow) * 1024 + scg * 16;
  unsigned char* awr0 = smem + 34816 + srow * 128 + (((scg * 2)     ^ (srow & 7)) << 4);
  unsigned char* awr1 = smem + 34816 + srow * 128 + (((scg * 2 + 1) ^ (srow & 7)) << 4);
  f32x4 areg[4];

  #define LOADX(ks)                                                       \
    { const f32x4* s_ = (const f32x4*)(xrow + (ks) * 64);                 \
      areg[0] = s_[0]; areg[1] = s_[1]; areg[2] = s_[2]; areg[3] = s_[3]; }
  #define WRITEA()                                                        \
    { uint4 u0, u1;                                                       \
      u0.x = cvtpk(areg[0].x, areg[0].y); u0.y = cvtpk(areg[0].z, areg[0].w); \
      u0.z = cvtpk(areg[1].x, areg[1].y); u0.w = cvtpk(areg[1].z, areg[1].w); \
      u1.x = cvtpk(areg[2].x, areg[2].y); u1.y = cvtpk(areg[2].z, areg[2].w); \
      u1.z = cvtpk(areg[3].x, areg[3].y); u1.w = cvtpk(areg[3].z, areg[3].w); \
      *(uint4*)awr0 = u0; *(uint4*)awr1 = u1; }
  #define STAGEB(ks)                                                      \
    { const unsigned char* bsrc_ = B1s + (ks) * B1S_KBSZ + lane * 16;     \
      for (int i = w; i < 34; i += 8) {                                   \
        int unit = (i < 32) ? (p * 32 + i) : (64 + (i - 32));             \
        async16(bsrc_ + unit * 1024, smem + i * 1024);                    \
      } }

  LOADX(0); STAGEB(0); WRITEA();
  __syncthreads();

  #pragma unroll 1
  for (int ks = 0; ks < 16; ++ks) {
    if (ks < 15) LOADX(ks + 1);  // global f32 loads fly under the MFMA cluster
    #pragma unroll
    for (int ksub = 0; ksub < 2; ++ksub) {
      const int ch = ((ksub * 4 + fhi) ^ (f15 & 7)) << 4;
      bf16x8 af[4];
      #pragma unroll
      for (int mf = 0; mf < 4; ++mf)
        af[mf] = *(const bf16x8*)(smem + 34816 + (mg * 64 + mf * 16 + f15) * 128 + ch);
      #pragma unroll
      for (int i = 0; i < 4; ++i) {
        bf16x8 bfr = *(const bf16x8*)(smem + (ng * 4 + i) * 2048 + f15 * 128 + ch);
        #pragma unroll
        for (int mf = 0; mf < 4; ++mf)
          acc[mf][i] = __builtin_amdgcn_mfma_f32_16x16x32_bf16(af[mf], bfr, acc[mf][i], 0, 0, 0);
      }
      if (ng == 0) {
        bf16x8 bfr = *(const bf16x8*)(smem + 16 * 2048 + f15 * 128 + ch);
        #pragma unroll
        for (int mf = 0; mf < 4; ++mf)
          acc[mf][4] = __builtin_amdgcn_mfma_f32_16x16x32_bf16(af[mf], bfr, acc[mf][4], 0, 0, 0);
      }
    }
    __syncthreads();
    if (ks < 15) {
      STAGEB(ks + 1);
      WRITEA();
      __syncthreads();
    }
  }

  float* logit_lds        = (float*)(smem + 34816);           // [128][8]
  unsigned short* pb      = (unsigned short*)(smem + 38912);  // [128][8]
  unsigned short* hb      = (unsigned short*)smem;            // [128][136]

  if (ng == 0 && f15 < 8) {  // router logits + br  (both quads compute all 8)
    float brv = br[f15];
    #pragma unroll
    for (int mf = 0; mf < 4; ++mf)
      #pragma unroll
      for (int r = 0; r < 4; ++r)
        logit_lds[(mg * 64 + mf * 16 + fhi * 4 + r) * 8 + f15] = acc[mf][4][r] + brv;
  }
  __syncthreads();

  const int e = p * 4 + ng;
  const float b1x0 = b1[e * 64 + f15],      b1x1 = b1[e * 64 + 16 + f15];
  const float b1g0 = b1[e * 64 + 32 + f15], b1g1 = b1[e * 64 + 48 + f15];

  #pragma unroll
  for (int mf = 0; mf < 4; ++mf) {
    #pragma unroll
    for (int r = 0; r < 4; ++r) {
      int row = mg * 64 + mf * 16 + fhi * 4 + r;
      const float* lg = logit_lds + row * 8;
      float l0 = lg[0], l1 = lg[1], l2 = lg[2], l3 = lg[3];
      float l4 = lg[4], l5 = lg[5], l6 = lg[6], l7 = lg[7];
      float mx = fmaxf(fmaxf(fmaxf(l0, l1), fmaxf(l2, l3)),
                       fmaxf(fmaxf(l4, l5), fmaxf(l6, l7)));
      float ssum = __expf(l0 - mx) + __expf(l1 - mx) + __expf(l2 - mx) + __expf(l3 - mx) +
                   __expf(l4 - mx) + __expf(l5 - mx) + __expf(l6 - mx) + __expf(l7 - mx);
      float rinv = 1.f / ssum;
      float pe = __expf(lg[e] - mx) * rinv;
      #pragma unroll
      for (int ci = 0; ci < 2; ++ci) {
        float xv = acc[mf][ci][r]     + (ci ? b1x1 : b1x0);
        float gv = acc[mf][ci + 2][r] + (ci ? b1g1 : b1g0);
        float av = pe * xv * gv / (1.f + __expf(-gv));  // pe * xp * silu(gate)
        hb[row * 136 + ng * 32 + ci * 16 + f15] = f2bf(av);
      }
      if (ng == 0 && f15 < 8) pb[row * 8 + f15] = f2bf(__expf(lg[f15] - mx) * rinv);
    }
  }
  __syncthreads();

  {  // ACT write: this quad's 128 k-cols (chunks p*16..p*16+15), quad0 appends p + zeros
    const int row = tid >> 2, q = tid & 3, key = row & 7;
    unsigned char* arow = ACT + (size_t)(m0 + row) * 640;
    #pragma unroll
    for (int j = 0; j < 4; ++j) {
      int c = q * 4 + j;
      uint4 v = *(const uint4*)((const unsigned char*)hb + row * 272 + c * 16);
      *(uint4*)(arow + p * 256 + (c & 8) * 16 + (((c & 7) ^ key) << 4)) = v;
    }
    if (p == 0) {
      #pragma unroll
      for (int j = 0; j < 2; ++j) {
        int c = q * 2 + j;
        uint4 v = make_uint4(0, 0, 0, 0);
        if (c == 0) v = *(const uint4*)((const unsigned char*)pb + row * 16);
        *(uint4*)(arow + 512 + ((c ^ key) << 4)) = v;
      }
    }
  }
}

// ---------------- kernel 2: ACT[32768,320] @ W2s[320,1024] -> out (f32) ----------------
// grid 512 = 128 m x 4 n; block 512 = 8 waves (4 wm x 2 wn), wave 64x128
__global__ __launch_bounds__(512, 4) void moe_gemm2(
    const unsigned char* __restrict__ ACT, const unsigned char* __restrict__ W2s,
    float* __restrict__ out) {
  __shared__ __align__(16) unsigned char smem[65536];  // A [0,32768) B [32768,65536)
  const int tid  = threadIdx.x;
  const int lane = tid & 63;
  const int w    = tid >> 6;
  const int wm   = w >> 1, wn = w & 1;
  const int f15  = lane & 15, fhi = lane >> 4;
  const int r8   = lane >> 3, c8 = lane & 7;

  const int wid = ((blockIdx.x & 7) << 6) + (blockIdx.x >> 3);  // 512 = 8*64
  const int m0  = (wid >> 2) * 256;
  const int n0  = (wid & 3) * 256;

  f32x4 acc[4][8];
  #pragma unroll
  for (int a = 0; a < 4; ++a)
    #pragma unroll
    for (int b = 0; b < 8; ++b) acc[a][b] = f32x4{0.f, 0.f, 0.f, 0.f};

  #define STAGE2(kb)                                                               \
    {                                                                              \
      for (int i = w; i < 32; i += 8) {                                            \
        async16(ACT + (size_t)(m0 + i * 8 + r8) * 640 + (kb) * 128 + c8 * 16,      \
                smem + i * 1024);                                                  \
        async16(W2s + (size_t)(n0 + i * 8 + r8) * 640 + (kb) * 128 + c8 * 16,      \
                smem + 32768 + i * 1024);                                          \
      }                                                                            \
    }

  STAGE2(0);
  __syncthreads();

  #pragma unroll 1
  for (int kb = 0; kb < 5; ++kb) {
    #pragma unroll
    for (int ksub = 0; ksub < 2; ++ksub) {
      const int ch = ((ksub * 4 + fhi) ^ (f15 & 7)) << 4;
      bf16x8 af[4];
      #pragma unroll
      for (int mf = 0; mf < 4; ++mf)
        af[mf] = *(const bf16x8*)(smem + (wm * 64 + mf * 16 + f15) * 128 + ch);
      #pragma unroll
      for (int nf = 0; nf < 8; ++nf) {
        bf16x8 bfr = *(const bf16x8*)(smem + 32768 + (wn * 128 + nf * 16 + f15) * 128 + ch);
        #pragma unroll
        for (int mf = 0; mf < 4; ++mf)
          acc[mf][nf] = __builtin_amdgcn_mfma_f32_16x16x32_bf16(af[mf], bfr, acc[mf][nf], 0, 0, 0);
      }
    }
    __syncthreads();
    if (kb < 4) {
      STAGE2(kb + 1);
      __syncthreads();
    }
  }

  float* ob = out + (size_t)(m0 + wm * 64 + fhi * 4) * 1024 + n0 + wn * 128 + f15;
  #pragma unroll
  for (int mf = 0; mf < 4; ++mf)
    #pragma unroll
    for (int nf = 0; nf < 8; ++nf)
      #pragma unroll
      for (int r = 0; r < 4; ++r)
        ob[(size_t)(mf * 16 + r) * 1024 + nf * 16] = acc[mf][nf][r];
}

extern "C" void kernel_launch(void* const* d_in, const int* in_sizes, int n_in,
                              void* d_out, int out_size, void* d_ws, size_t ws_size,
                              hipStream_t stream) {
  const float* x  = (const float*)d_in[0];
  const float* Wr = (const float*)d_in[1];
  const float* br = (const float*)d_in[2];
  const float* W1 = (const float*)d_in[3];
  const float* b1 = (const float*)d_in[4];
  const float* W2 = (const float*)d_in[5];
  const float* b2 = (const float*)d_in[6];
  float* out = (float*)d_out;
  unsigned char* ws  = (unsigned char*)d_ws;
  unsigned char* B1s = ws;
  unsigned char* W2s = ws + W2S_OFF;
  unsigned char* ACT = ws + ACT_OFF;

  hipLaunchKernelGGL(prep_all, dim3(37), dim3(256), 0, stream, W1, Wr, W2, b2, B1s, W2s);
  hipLaunchKernelGGL(moe_gemm1, dim3(512), dim3(512), 0, stream, x, br, b1, B1s, ACT);
  hipLaunchKernelGGL(moe_gemm2, dim3(512), dim3(512), 0, stream, ACT, W2s, out);
}

// Round 5
// 206.883 us; speedup vs baseline: 1.4336x; 1.4336x over previous
//
#include <hip/hip_runtime.h>

typedef float f32x4 __attribute__((ext_vector_type(4)));
typedef short bf16x8 __attribute__((ext_vector_type(8)));

// ---- workspace layout (bytes) ----
// B1s: [16 kb][528 cols][128 B]  (bf16, chunk-swizzled; cols 512-519 router, 520-527 zero)
// W2s: [1024 cols][640 B]        (bf16, chunk-swizzled; rows 256-263 = b2, 264-319 zero)
// ACT: [32768 rows][640 B]       (bf16, chunk-swizzled; k 256-263 = p, 264-319 zero)
#define B1S_KBSZ 67584
#define W2S_OFF  1081344
#define ACT_OFF  1736704
// total ws required: 22,708,224 bytes

__device__ __forceinline__ unsigned short f2bf(float f) {
  unsigned int u = __float_as_uint(f);
  return (unsigned short)((u + 0x7FFFu + ((u >> 16) & 1u)) >> 16);
}
__device__ __forceinline__ unsigned int pack2(float a, float b) {
  return (unsigned int)f2bf(a) | ((unsigned int)f2bf(b) << 16);
}
__device__ __forceinline__ unsigned int cvtpk(float a, float b) {
  unsigned int r;
  asm("v_cvt_pk_bf16_f32 %0, %1, %2" : "=v"(r) : "v"(a), "v"(b));
  return r;
}
__device__ __forceinline__ void async16(const void* g, void* l) {
  __builtin_amdgcn_global_load_lds(
      (const __attribute__((address_space(1))) unsigned int*)g,
      (__attribute__((address_space(3))) unsigned int*)l, 16, 0, 0);
}

// ---------------- prep: pack [W1|Wr|0] -> B1s ; [W2;b2;0] -> W2s ----------------
__global__ __launch_bounds__(256) void prep_all(const float* __restrict__ W1,
                                                const float* __restrict__ Wr,
                                                const float* __restrict__ W2,
                                                const float* __restrict__ b2,
                                                unsigned char* __restrict__ B1s,
                                                unsigned char* __restrict__ W2s) {
  if (blockIdx.x < 33) {
    int t = blockIdx.x * 256 + threadIdx.x;
    if (t >= 528 * 16) return;
    int col = t % 528;
    int kb  = t / 528;
    unsigned char* dst = B1s + kb * B1S_KBSZ + col * 128;
    int key = col & 7;
    int e   = col >> 6;
    int hh  = col & 63;
    #pragma unroll
    for (int c = 0; c < 8; ++c) {
      float v[8];
      #pragma unroll
      for (int jj = 0; jj < 8; ++jj) {
        int k = kb * 64 + c * 8 + jj;
        float f;
        if (col < 512)      f = W1[(e * 1024 + k) * 64 + hh];   // W1[e][k][hh]
        else if (col < 520) f = Wr[k * 8 + (col - 512)];        // Wr[k][e]
        else                f = 0.0f;
        v[jj] = f;
      }
      *(uint4*)(dst + ((c ^ key) * 16)) =
          make_uint4(pack2(v[0], v[1]), pack2(v[2], v[3]), pack2(v[4], v[5]), pack2(v[6], v[7]));
    }
  } else {
    int c = (blockIdx.x - 33) * 256 + threadIdx.x;
    if (c >= 1024) return;
    unsigned char* dst = W2s + c * 640;
    int key = c & 7;
    #pragma unroll 1
    for (int cj = 0; cj < 40; ++cj) {
      float v[8];
      #pragma unroll
      for (int jj = 0; jj < 8; ++jj) {
        int k = cj * 8 + jj;
        float f;
        if (k < 256)      f = W2[k * 1024 + c];          // W2[e][h][c], k=e*32+h
        else if (k < 264) f = b2[(k - 256) * 1024 + c];  // b2[e][c]
        else              f = 0.0f;
        v[jj] = f;
      }
      int dstc = (cj & ~7) | ((cj & 7) ^ key);
      *(uint4*)(dst + dstc * 16) =
          make_uint4(pack2(v[0], v[1]), pack2(v[2], v[3]), pack2(v[4], v[5]), pack2(v[6], v[7]));
    }
  }
}

// ---------------- kernel 1: 128x144 pair tile, dbuf + issue-early, 1 barrier/step ----------------
// grid 1024 = 256 M-tiles x 4 pairs; block 512 = 8 waves (4 mg x 2 ng), wave 32x80/64
__global__ __launch_bounds__(512, 4) void moe_gemm1(
    const float* __restrict__ x, const float* __restrict__ br, const float* __restrict__ b1,
    const unsigned char* __restrict__ B1s, unsigned char* __restrict__ ACT) {
  __shared__ __align__(16) unsigned char smem[69632];
  // bb[2] @ 0 / 18432 ; ab[2] @ 36864 / 53248
  // epilogue aliases: hb u16[128][72] (144B stride) @ 0 ; logit f32[128][8] @ 36864 ; pb @ 40960

  const int tid  = threadIdx.x;
  const int lane = tid & 63;
  const int w    = tid >> 6;
  const int mg   = w >> 1;   // rows mg*32 .. +32
  const int ng   = w & 1;    // 0: pair-frags 0-3 + router ; 1: pair-frags 4-7
  const int f15  = lane & 15;
  const int fhi  = lane >> 4;

  const int wid   = ((blockIdx.x & 7) << 7) + (blockIdx.x >> 3);  // XCD-chunked, 1024=8*128
  const int mtile = wid >> 2;
  const int p     = wid & 3;
  const int m0    = mtile << 7;

  f32x4 acc[2][5];
  #pragma unroll
  for (int a = 0; a < 2; ++a)
    #pragma unroll
    for (int b = 0; b < 5; ++b) acc[a][b] = f32x4{0.f, 0.f, 0.f, 0.f};

  // A staging: thread = (row tid>>2, 16-float chunk tid&3)
  const int srow = tid >> 2;
  const int scg  = tid & 3;
  const float* xrow = x + (size_t)(m0 + srow) * 1024 + scg * 16;
  const int awo0 = srow * 128 + (((scg * 2)     ^ (srow & 7)) << 4);
  const int awo1 = srow * 128 + (((scg * 2 + 1) ^ (srow & 7)) << 4);
  f32x4 areg[4];

  #define LOADX(ks)                                                       \
    { const f32x4* s_ = (const f32x4*)(xrow + (ks) * 64);                 \
      areg[0] = s_[0]; areg[1] = s_[1]; areg[2] = s_[2]; areg[3] = s_[3]; }
  #define WRITEA(buf)                                                     \
    { unsigned char* ab_ = smem + 36864 + (buf) * 16384;                  \
      uint4 u0, u1;                                                       \
      u0.x = cvtpk(areg[0].x, areg[0].y); u0.y = cvtpk(areg[0].z, areg[0].w); \
      u0.z = cvtpk(areg[1].x, areg[1].y); u0.w = cvtpk(areg[1].z, areg[1].w); \
      u1.x = cvtpk(areg[2].x, areg[2].y); u1.y = cvtpk(areg[2].z, areg[2].w); \
      u1.z = cvtpk(areg[3].x, areg[3].y); u1.w = cvtpk(areg[3].z, areg[3].w); \
      *(uint4*)(ab_ + awo0) = u0; *(uint4*)(ab_ + awo1) = u1; }
  #define STAGEB(ks, buf)                                                 \
    { const unsigned char* bsrc_ = B1s + (ks) * B1S_KBSZ + lane * 16;     \
      unsigned char* bb_ = smem + (buf) * 18432;                          \
      for (int i = w; i < 18; i += 8) {                                   \
        int unit = (i < 16) ? (p * 16 + i) : (64 + (i - 16));             \
        async16(bsrc_ + unit * 1024, bb_ + i * 1024);                     \
      } }

  int bco[5];
  #pragma unroll
  for (int i = 0; i < 5; ++i) {
    int cf = ng ? (4 + i) : (i < 4 ? i : 8);
    bco[i] = (cf * 16 + f15) * 128;
  }

  LOADX(0); STAGEB(0, 0); WRITEA(0); LOADX(1);
  __syncthreads();

  #pragma unroll 1
  for (int ks = 0; ks < 16; ++ks) {
    const int cur = ks & 1;
    if (ks < 15) {
      STAGEB(ks + 1, cur ^ 1);   // async loads fly under the MFMA cluster
      WRITEA(cur ^ 1);           // areg holds x(ks+1)
      if (ks < 14) LOADX(ks + 2);
    }
    const unsigned char* bb = smem + cur * 18432;
    const unsigned char* ab = smem + 36864 + cur * 16384;
    #pragma unroll
    for (int ksub = 0; ksub < 2; ++ksub) {
      const int ch = ((ksub * 4 + fhi) ^ (f15 & 7)) << 4;
      bf16x8 af0 = *(const bf16x8*)(ab + (mg * 32      + f15) * 128 + ch);
      bf16x8 af1 = *(const bf16x8*)(ab + (mg * 32 + 16 + f15) * 128 + ch);
      #pragma unroll
      for (int i = 0; i < 4; ++i) {
        bf16x8 bfr = *(const bf16x8*)(bb + bco[i] + ch);
        acc[0][i] = __builtin_amdgcn_mfma_f32_16x16x32_bf16(af0, bfr, acc[0][i], 0, 0, 0);
        acc[1][i] = __builtin_amdgcn_mfma_f32_16x16x32_bf16(af1, bfr, acc[1][i], 0, 0, 0);
      }
      if (ng == 0) {
        bf16x8 bfr = *(const bf16x8*)(bb + bco[4] + ch);
        acc[0][4] = __builtin_amdgcn_mfma_f32_16x16x32_bf16(af0, bfr, acc[0][4], 0, 0, 0);
        acc[1][4] = __builtin_amdgcn_mfma_f32_16x16x32_bf16(af1, bfr, acc[1][4], 0, 0, 0);
      }
    }
    __syncthreads();
  }

  float* logit_lds   = (float*)(smem + 36864);           // [128][8]
  unsigned short* pb = (unsigned short*)(smem + 40960);  // [128][8]
  unsigned short* hb = (unsigned short*)smem;            // [128][72] (144 B stride)

  if (ng == 0 && f15 < 8) {  // router logits + br
    float brv = br[f15];
    #pragma unroll
    for (int mf = 0; mf < 2; ++mf)
      #pragma unroll
      for (int r = 0; r < 4; ++r)
        logit_lds[(mg * 32 + mf * 16 + fhi * 4 + r) * 8 + f15] = acc[mf][4][r] + brv;
  }
  __syncthreads();

  const int e = p * 2 + ng;
  const float b1x0 = b1[e * 64 + f15],      b1x1 = b1[e * 64 + 16 + f15];
  const float b1g0 = b1[e * 64 + 32 + f15], b1g1 = b1[e * 64 + 48 + f15];

  #pragma unroll
  for (int mf = 0; mf < 2; ++mf) {
    #pragma unroll
    for (int r = 0; r < 4; ++r) {
      int row = mg * 32 + mf * 16 + fhi * 4 + r;
      const float* lg = logit_lds + row * 8;
      float l0 = lg[0], l1 = lg[1], l2 = lg[2], l3 = lg[3];
      float l4 = lg[4], l5 = lg[5], l6 = lg[6], l7 = lg[7];
      float mx = fmaxf(fmaxf(fmaxf(l0, l1), fmaxf(l2, l3)),
                       fmaxf(fmaxf(l4, l5), fmaxf(l6, l7)));
      float ssum = __expf(l0 - mx) + __expf(l1 - mx) + __expf(l2 - mx) + __expf(l3 - mx) +
                   __expf(l4 - mx) + __expf(l5 - mx) + __expf(l6 - mx) + __expf(l7 - mx);
      float rinv = 1.f / ssum;
      float pe = __expf(lg[e] - mx) * rinv;
      #pragma unroll
      for (int ci = 0; ci < 2; ++ci) {
        float xv = acc[mf][ci][r]     + (ci ? b1x1 : b1x0);
        float gv = acc[mf][ci + 2][r] + (ci ? b1g1 : b1g0);
        float av = pe * xv * gv / (1.f + __expf(-gv));  // pe * xp * silu(gate)
        hb[row * 72 + ng * 32 + ci * 16 + f15] = f2bf(av);
      }
      if (ng == 0 && f15 < 8) pb[row * 8 + f15] = f2bf(__expf(lg[f15] - mx) * rinv);
    }
  }
  __syncthreads();

  {  // ACT write: 8 chunks of this pair (+ p/zero chunks from pair 0)
    const int row = tid >> 2, q = tid & 3, key = row & 7;
    unsigned char* arow = ACT + (size_t)(m0 + row) * 640;
    #pragma unroll
    for (int j = 0; j < 2; ++j) {
      int c = q * 2 + j;  // 0..7
      uint4 v = *(const uint4*)((const unsigned char*)hb + row * 144 + c * 16);
      *(uint4*)(arow + p * 128 + ((c ^ key) << 4)) = v;
    }
    if (p == 0) {  // k 256-263 = p ; k 264-319 = 0
      #pragma unroll
      for (int j = 0; j < 2; ++j) {
        int c = q * 2 + j;
        uint4 v = make_uint4(0, 0, 0, 0);
        if (c == 0) v = *(const uint4*)((const unsigned char*)pb + row * 16);
        *(uint4*)(arow + 512 + ((c ^ key) << 4)) = v;
      }
    }
  }
}

// ---------------- kernel 2: ACT[32768,320] @ W2s[320,1024], dbuf + LDS-transpose epilogue ----------------
// grid 2048 = 256 m x 8 n; block 512 = 8 waves (2 wm x 4 wn), wave 64x32
__global__ __launch_bounds__(512, 4) void moe_gemm2(
    const unsigned char* __restrict__ ACT, const unsigned char* __restrict__ W2s,
    float* __restrict__ out) {
  __shared__ __align__(16) unsigned char smem[65536];
  // ab[2] @ 0 / 16384 ; bb[2] @ 32768 / 49152 ; epilogue slab f32[128][128] @ 0
  const int tid  = threadIdx.x;
  const int lane = tid & 63;
  const int w    = tid >> 6;
  const int wm   = w >> 2, wn = w & 3;
  const int f15  = lane & 15, fhi = lane >> 4;
  const int r8   = lane >> 3, c8 = lane & 7;

  const int wid = ((blockIdx.x & 7) << 8) + (blockIdx.x >> 3);  // 2048 = 8*256
  const int m0  = (wid >> 3) * 128;
  const int n0  = (wid & 7) * 128;

  f32x4 acc[4][2];
  #pragma unroll
  for (int a = 0; a < 4; ++a)
    #pragma unroll
    for (int b = 0; b < 2; ++b) acc[a][b] = f32x4{0.f, 0.f, 0.f, 0.f};

  #define STAGE2(kb, buf)                                                          \
    {                                                                              \
      for (int i = w; i < 16; i += 8) {                                            \
        async16(ACT + (size_t)(m0 + i * 8 + r8) * 640 + (kb) * 128 + c8 * 16,      \
                smem + (buf) * 16384 + i * 1024);                                  \
        async16(W2s + (size_t)(n0 + i * 8 + r8) * 640 + (kb) * 128 + c8 * 16,      \
                smem + 32768 + (buf) * 16384 + i * 1024);                          \
      }                                                                            \
    }

  STAGE2(0, 0);
  __syncthreads();

  #pragma unroll 1
  for (int kb = 0; kb < 5; ++kb) {
    const int cur = kb & 1;
    if (kb < 4) STAGE2(kb + 1, cur ^ 1);  // issue-early: flies under MFMA
    const unsigned char* ab = smem + cur * 16384;
    const unsigned char* bb = smem + 32768 + cur * 16384;
    #pragma unroll
    for (int ksub = 0; ksub < 2; ++ksub) {
      const int ch = ((ksub * 4 + fhi) ^ (f15 & 7)) << 4;
      bf16x8 af[4];
      #pragma unroll
      for (int mf = 0; mf < 4; ++mf)
        af[mf] = *(const bf16x8*)(ab + (wm * 64 + mf * 16 + f15) * 128 + ch);
      #pragma unroll
      for (int nf = 0; nf < 2; ++nf) {
        bf16x8 bfr = *(const bf16x8*)(bb + ((wn * 32 + nf * 16) + f15) * 128 + ch);
        #pragma unroll
        for (int mf = 0; mf < 4; ++mf)
          acc[mf][nf] = __builtin_amdgcn_mfma_f32_16x16x32_bf16(af[mf], bfr, acc[mf][nf], 0, 0, 0);
      }
    }
    __syncthreads();
  }

  // epilogue: acc -> swizzled f32 slab [128][128] -> fully-coalesced 512B row stores
  float* slab = (float*)smem;
  #pragma unroll
  for (int mf = 0; mf < 4; ++mf) {
    #pragma unroll
    for (int nf = 0; nf < 2; ++nf) {
      #pragma unroll
      for (int r = 0; r < 4; ++r) {
        int row = wm * 64 + mf * 16 + fhi * 4 + r;
        int col = wn * 32 + nf * 16 + f15;
        slab[row * 128 + (col ^ ((row & 7) << 2))] = acc[mf][nf][r];
      }
    }
  }
  __syncthreads();
  {
    const int l  = lane & 31;
    const int rh = lane >> 5;
    #pragma unroll
    for (int j = 0; j < 8; ++j) {
      int row = w * 16 + j * 2 + rh;
      f32x4 v = *(const f32x4*)(smem + row * 512 + ((l ^ (row & 7)) << 4));
      *(f32x4*)(out + (size_t)(m0 + row) * 1024 + n0 + l * 4) = v;
    }
  }
}

extern "C" void kernel_launch(void* const* d_in, const int* in_sizes, int n_in,
                              void* d_out, int out_size, void* d_ws, size_t ws_size,
                              hipStream_t stream) {
  const float* x  = (const float*)d_in[0];
  const float* Wr = (const float*)d_in[1];
  const float* br = (const float*)d_in[2];
  const float* W1 = (const float*)d_in[3];
  const float* b1 = (const float*)d_in[4];
  const float* W2 = (const float*)d_in[5];
  const float* b2 = (const float*)d_in[6];
  float* out = (float*)d_out;
  unsigned char* ws  = (unsigned char*)d_ws;
  unsigned char* B1s = ws;
  unsigned char* W2s = ws + W2S_OFF;
  unsigned char* ACT = ws + ACT_OFF;

  hipLaunchKernelGGL(prep_all, dim3(37), dim3(256), 0, stream, W1, Wr, W2, b2, B1s, W2s);
  hipLaunchKernelGGL(moe_gemm1, dim3(1024), dim3(512), 0, stream, x, br, b1, B1s, ACT);
  hipLaunchKernelGGL(moe_gemm2, dim3(2048), dim3(512), 0, stream, ACT, W2s, out);
}

// Round 6
// 192.467 us; speedup vs baseline: 1.5410x; 1.0749x over previous
//
#include <hip/hip_runtime.h>

typedef float f32x4 __attribute__((ext_vector_type(4)));
typedef short bf16x8 __attribute__((ext_vector_type(8)));

// ---- workspace layout (bytes) ----
// B1s: [16 kb][528 cols][128 B]  (bf16, chunk-swizzled; cols 512-519 router, 520-527 zero)
// W2s: [1024 cols][640 B]        (bf16, chunk-swizzled; rows 256-263 = b2, 264-319 zero)
// ACT: [32768 rows][640 B]       (bf16, chunk-swizzled; k 256-263 = p, 264-319 zero)
#define B1S_KBSZ 67584
#define W2S_OFF  1081344
#define ACT_OFF  1736704
// total ws required: 22,708,224 bytes

__device__ __forceinline__ unsigned short f2bf(float f) {
  unsigned int u = __float_as_uint(f);
  return (unsigned short)((u + 0x7FFFu + ((u >> 16) & 1u)) >> 16);
}
__device__ __forceinline__ unsigned int pack2(float a, float b) {
  return (unsigned int)f2bf(a) | ((unsigned int)f2bf(b) << 16);
}
__device__ __forceinline__ unsigned int cvtpk(float a, float b) {
  unsigned int r;
  asm("v_cvt_pk_bf16_f32 %0, %1, %2" : "=v"(r) : "v"(a), "v"(b));
  return r;
}
__device__ __forceinline__ bf16x8 cvt8(f32x4 lo, f32x4 hi) {
  union { uint4 u; bf16x8 b; } r;
  r.u.x = cvtpk(lo.x, lo.y); r.u.y = cvtpk(lo.z, lo.w);
  r.u.z = cvtpk(hi.x, hi.y); r.u.w = cvtpk(hi.z, hi.w);
  return r.b;
}
__device__ __forceinline__ void async16(const void* g, void* l) {
  __builtin_amdgcn_global_load_lds(
      (const __attribute__((address_space(1))) unsigned int*)g,
      (__attribute__((address_space(3))) unsigned int*)l, 16, 0, 0);
}

// ---------------- prep: pack [W1|Wr|0] -> B1s ; [W2;b2;0] -> W2s ----------------
// blocks 0-263: B1s, one thread per (kb, col, chunk)  (67584 threads)
// blocks 264-423: W2s, one thread per (col, cj)       (40960 threads)
__global__ __launch_bounds__(256) void prep_all(const float* __restrict__ W1,
                                                const float* __restrict__ Wr,
                                                const float* __restrict__ W2,
                                                const float* __restrict__ b2,
                                                unsigned char* __restrict__ B1s,
                                                unsigned char* __restrict__ W2s) {
  if (blockIdx.x < 264) {
    int t = blockIdx.x * 256 + threadIdx.x;
    int c   = t & 7;
    int col = (t >> 3) % 528;
    int kb  = (t >> 3) / 528;
    int e   = col >> 6;
    int hh  = col & 63;
    float v[8];
    #pragma unroll
    for (int jj = 0; jj < 8; ++jj) {
      int k = kb * 64 + c * 8 + jj;
      float f;
      if (col < 512)      f = W1[(e * 1024 + k) * 64 + hh];   // W1[e][k][hh]
      else if (col < 520) f = Wr[k * 8 + (col - 512)];        // Wr[k][e]
      else                f = 0.0f;
      v[jj] = f;
    }
    *(uint4*)(B1s + kb * B1S_KBSZ + col * 128 + ((c ^ (col & 7)) * 16)) =
        make_uint4(pack2(v[0], v[1]), pack2(v[2], v[3]), pack2(v[4], v[5]), pack2(v[6], v[7]));
  } else {
    int t = (blockIdx.x - 264) * 256 + threadIdx.x;
    int cj  = t % 40;
    int col = t / 40;
    float v[8];
    #pragma unroll
    for (int jj = 0; jj < 8; ++jj) {
      int k = cj * 8 + jj;
      float f;
      if (k < 256)      f = W2[k * 1024 + col];          // W2[e][h][c], k=e*32+h
      else if (k < 264) f = b2[(k - 256) * 1024 + col];  // b2[e][c]
      else              f = 0.0f;
      v[jj] = f;
    }
    int dstc = (cj & ~7) | ((cj & 7) ^ (col & 7));
    *(uint4*)(W2s + col * 640 + dstc * 16) =
        make_uint4(pack2(v[0], v[1]), pack2(v[2], v[3]), pack2(v[4], v[5]), pack2(v[6], v[7]));
  }
}

// ---------------- kernel 1: 128x144 pair tile, reg-staged A, B-only LDS (dbuf) ----------------
// grid 1024 = 256 M-tiles x 4 pairs; block 256 = 4 waves (2 mg x 2 ng), wave 64x80/64
__global__ __launch_bounds__(256, 3) void moe_gemm1(
    const float* __restrict__ x, const float* __restrict__ br, const float* __restrict__ b1,
    const unsigned char* __restrict__ B1s, unsigned char* __restrict__ ACT) {
  __shared__ __align__(16) unsigned char smem[40960];
  // bb[2] @ 0 / 18432 ; logit f32[128][8] @ 36864
  // epilogue aliases: hb u16[128][72] @ 0 ; pb u16[128][8] @ 18432

  const int tid  = threadIdx.x;
  const int lane = tid & 63;
  const int w    = tid >> 6;   // 4 waves
  const int mg   = w >> 1;     // rows mg*64 .. +64
  const int ng   = w & 1;      // 0: pair frags 0-3 + router ; 1: pair frags 4-7
  const int f15  = lane & 15;
  const int fhi  = lane >> 4;

  const int wid   = ((blockIdx.x & 7) << 7) + (blockIdx.x >> 3);  // XCD-chunked, 1024=8*128
  const int mtile = wid >> 2;
  const int p     = wid & 3;
  const int m0    = mtile << 7;

  f32x4 acc[4][5];
  #pragma unroll
  for (int a = 0; a < 4; ++a)
    #pragma unroll
    for (int b = 0; b < 5; ++b) acc[a][b] = f32x4{0.f, 0.f, 0.f, 0.f};

  // per-lane A row base: row = m0 + mg*64 + mf*16 + f15, k-octet = fhi*8
  const float* xA = x + (size_t)(m0 + mg * 64 + f15) * 1024 + fhi * 8;

  int bco[5];
  #pragma unroll
  for (int i = 0; i < 5; ++i) {
    int cf = ng ? (4 + i) : (i < 4 ? i : 8);
    bco[i] = (cf * 16 + f15) * 128;
  }

  #define STAGEB(ks, buf)                                                 \
    { const unsigned char* bsrc_ = B1s + (ks) * B1S_KBSZ + lane * 16;     \
      unsigned char* bb_ = smem + (buf) * 18432;                          \
      for (int i = w; i < 18; i += 4) {                                   \
        int unit = (i < 16) ? (p * 16 + i) : (64 + (i - 16));             \
        async16(bsrc_ + unit * 1024, bb_ + i * 1024);                     \
      } }

  #define CLUSTER(af, ksub)                                                        \
    { const int ch = (((ksub) * 4 + fhi) ^ (f15 & 7)) << 4;                        \
      bf16x8 bf0 = *(const bf16x8*)(bb + bco[0] + ch);                             \
      bf16x8 bf1 = *(const bf16x8*)(bb + bco[1] + ch);                             \
      bf16x8 bf2 = *(const bf16x8*)(bb + bco[2] + ch);                             \
      bf16x8 bf3 = *(const bf16x8*)(bb + bco[3] + ch);                             \
      _Pragma("unroll")                                                            \
      for (int mf = 0; mf < 4; ++mf) {                                             \
        acc[mf][0] = __builtin_amdgcn_mfma_f32_16x16x32_bf16(af[mf], bf0, acc[mf][0], 0, 0, 0); \
        acc[mf][1] = __builtin_amdgcn_mfma_f32_16x16x32_bf16(af[mf], bf1, acc[mf][1], 0, 0, 0); \
        acc[mf][2] = __builtin_amdgcn_mfma_f32_16x16x32_bf16(af[mf], bf2, acc[mf][2], 0, 0, 0); \
        acc[mf][3] = __builtin_amdgcn_mfma_f32_16x16x32_bf16(af[mf], bf3, acc[mf][3], 0, 0, 0); \
      }                                                                            \
      if (ng == 0) {                                                               \
        bf16x8 bf4 = *(const bf16x8*)(bb + bco[4] + ch);                           \
        _Pragma("unroll")                                                          \
        for (int mf = 0; mf < 4; ++mf)                                             \
          acc[mf][4] = __builtin_amdgcn_mfma_f32_16x16x32_bf16(af[mf], bf4, acc[mf][4], 0, 0, 0); \
      } }

  STAGEB(0, 0);
  __syncthreads();

  #pragma unroll 1
  for (int ks = 0; ks < 16; ++ks) {
    const int cur = ks & 1;
    const float* xk = xA + ks * 64;
    // A loads (both ksubs) BEFORE the async16 stage so their waits never drain it
    f32x4 a0[4], a1[4], c0[4], c1[4];
    #pragma unroll
    for (int mf = 0; mf < 4; ++mf) {
      const float* s_ = xk + mf * 16384;
      a0[mf] = *(const f32x4*)s_;
      a1[mf] = *(const f32x4*)(s_ + 4);
    }
    bf16x8 af0[4];
    #pragma unroll
    for (int mf = 0; mf < 4; ++mf) af0[mf] = cvt8(a0[mf], a1[mf]);
    #pragma unroll
    for (int mf = 0; mf < 4; ++mf) {
      const float* s_ = xk + mf * 16384 + 32;
      c0[mf] = *(const f32x4*)s_;
      c1[mf] = *(const f32x4*)(s_ + 4);
    }
    if (ks < 15) STAGEB(ks + 1, cur ^ 1);
    const unsigned char* bb = smem + cur * 18432;
    CLUSTER(af0, 0);
    bf16x8 af1[4];
    #pragma unroll
    for (int mf = 0; mf < 4; ++mf) af1[mf] = cvt8(c0[mf], c1[mf]);
    CLUSTER(af1, 1);
    __syncthreads();
  }

  float* logit_lds   = (float*)(smem + 36864);           // [128][8]
  unsigned short* pb = (unsigned short*)(smem + 18432);  // [128][8]
  unsigned short* hb = (unsigned short*)smem;            // [128][72] (144 B stride)

  if (ng == 0 && f15 < 8) {  // router logits + br
    float brv = br[f15];
    #pragma unroll
    for (int mf = 0; mf < 4; ++mf)
      #pragma unroll
      for (int r = 0; r < 4; ++r)
        logit_lds[(mg * 64 + mf * 16 + fhi * 4 + r) * 8 + f15] = acc[mf][4][r] + brv;
  }
  __syncthreads();

  const int e = p * 2 + ng;
  const float b1x0 = b1[e * 64 + f15],      b1x1 = b1[e * 64 + 16 + f15];
  const float b1g0 = b1[e * 64 + 32 + f15], b1g1 = b1[e * 64 + 48 + f15];

  #pragma unroll
  for (int mf = 0; mf < 4; ++mf) {
    #pragma unroll
    for (int r = 0; r < 4; ++r) {
      int row = mg * 64 + mf * 16 + fhi * 4 + r;
      const float* lg = logit_lds + row * 8;
      float l0 = lg[0], l1 = lg[1], l2 = lg[2], l3 = lg[3];
      float l4 = lg[4], l5 = lg[5], l6 = lg[6], l7 = lg[7];
      float mx = fmaxf(fmaxf(fmaxf(l0, l1), fmaxf(l2, l3)),
                       fmaxf(fmaxf(l4, l5), fmaxf(l6, l7)));
      float ssum = __expf(l0 - mx) + __expf(l1 - mx) + __expf(l2 - mx) + __expf(l3 - mx) +
                   __expf(l4 - mx) + __expf(l5 - mx) + __expf(l6 - mx) + __expf(l7 - mx);
      float rinv = 1.f / ssum;
      float pe = __expf(lg[e] - mx) * rinv;
      #pragma unroll
      for (int ci = 0; ci < 2; ++ci) {
        float xv = acc[mf][ci][r]     + (ci ? b1x1 : b1x0);
        float gv = acc[mf][ci + 2][r] + (ci ? b1g1 : b1g0);
        float av = pe * xv * gv / (1.f + __expf(-gv));  // pe * xp * silu(gate)
        hb[row * 72 + ng * 32 + ci * 16 + f15] = f2bf(av);
      }
      if (ng == 0 && f15 < 8) pb[row * 8 + f15] = f2bf(__expf(lg[f15] - mx) * rinv);
    }
  }
  __syncthreads();

  {  // ACT write: this pair's 8 chunks (+ p/zero chunks from pair 0)
    const int row = tid >> 1, q = tid & 1, key = row & 7;
    unsigned char* arow = ACT + (size_t)(m0 + row) * 640;
    #pragma unroll
    for (int j = 0; j < 4; ++j) {
      int c = q * 4 + j;  // 0..7
      uint4 v = *(const uint4*)((const unsigned char*)hb + row * 144 + c * 16);
      *(uint4*)(arow + p * 128 + ((c ^ key) << 4)) = v;
    }
    if (p == 0) {  // k 256-263 = p ; k 264-319 = 0
      #pragma unroll
      for (int j = 0; j < 4; ++j) {
        int c = q * 4 + j;
        uint4 v = make_uint4(0, 0, 0, 0);
        if (c == 0) v = *(const uint4*)((const unsigned char*)pb + row * 16);
        *(uint4*)(arow + 512 + ((c ^ key) << 4)) = v;
      }
    }
  }
}

// ---------------- kernel 2: ACT[32768,320] @ W2s[320,1024], reg-staged A, dbuf B ----------------
// grid 2048 = 256 m x 8 n; block 256 = 4 waves (2x2), wave 64x64
__global__ __launch_bounds__(256, 4) void moe_gemm2(
    const unsigned char* __restrict__ ACT, const unsigned char* __restrict__ W2s,
    float* __restrict__ out) {
  __shared__ __align__(16) unsigned char smem[32768];  // bb[2] 2x16KB ; epilogue slab f32[64][128]
  const int tid  = threadIdx.x;
  const int lane = tid & 63;
  const int w    = tid >> 6;
  const int wm   = w >> 1, wn = w & 1;
  const int f15  = lane & 15, fhi = lane >> 4;
  const int r8   = lane >> 3, c8 = lane & 7;

  const int wid = ((blockIdx.x & 7) << 8) + (blockIdx.x >> 3);  // 2048 = 8*256
  const int m0  = (wid >> 3) * 128;
  const int n0  = (wid & 7) * 128;

  f32x4 acc[4][4];
  #pragma unroll
  for (int a = 0; a < 4; ++a)
    #pragma unroll
    for (int b = 0; b < 4; ++b) acc[a][b] = f32x4{0.f, 0.f, 0.f, 0.f};

  // per-lane A row base (ACT rows are chunk-swizzled with key = row&7 = f15&7)
  const unsigned char* aA = ACT + (size_t)(m0 + wm * 64 + f15) * 640;
  const int ch0 = ((fhi)     ^ (f15 & 7)) << 4;
  const int ch1 = ((4 + fhi) ^ (f15 & 7)) << 4;

  #define STG2(kb, buf)                                                            \
    { for (int i = w; i < 16; i += 4)                                              \
        async16(W2s + (size_t)(n0 + i * 8 + r8) * 640 + (kb) * 128 + c8 * 16,      \
                smem + (buf) * 16384 + i * 1024); }

  STG2(0, 0);
  __syncthreads();

  #pragma unroll 1
  for (int kb = 0; kb < 5; ++kb) {
    const int cur = kb & 1;
    bf16x8 af0[4], af1[4];
    #pragma unroll
    for (int mf = 0; mf < 4; ++mf) {
      const unsigned char* s_ = aA + mf * 10240 + kb * 128;
      af0[mf] = *(const bf16x8*)(s_ + ch0);
      af1[mf] = *(const bf16x8*)(s_ + ch1);
    }
    if (kb < 4) STG2(kb + 1, cur ^ 1);
    const unsigned char* bb = smem + cur * 16384;
    #pragma unroll
    for (int ksub = 0; ksub < 2; ++ksub) {
      const int ch = ((ksub * 4 + fhi) ^ (f15 & 7)) << 4;
      #pragma unroll
      for (int nf = 0; nf < 4; ++nf) {
        bf16x8 bfr = *(const bf16x8*)(bb + (wn * 64 + nf * 16 + f15) * 128 + ch);
        #pragma unroll
        for (int mf = 0; mf < 4; ++mf)
          acc[mf][nf] = __builtin_amdgcn_mfma_f32_16x16x32_bf16(
              ksub ? af1[mf] : af0[mf], bfr, acc[mf][nf], 0, 0, 0);
      }
    }
    __syncthreads();
  }

  // epilogue: two 64-row rounds through a swizzled f32 slab -> 512B coalesced stores
  float* slab = (float*)smem;
  #pragma unroll 1
  for (int q = 0; q < 2; ++q) {
    if (wm == q) {
      #pragma unroll
      for (int mf = 0; mf < 4; ++mf)
        #pragma unroll
        for (int nf = 0; nf < 4; ++nf)
          #pragma unroll
          for (int r = 0; r < 4; ++r) {
            int rl  = mf * 16 + fhi * 4 + r;
            int col = wn * 64 + nf * 16 + f15;
            slab[rl * 128 + (col ^ (((rl >> 2) & 7) << 2))] = acc[mf][nf][r];
          }
    }
    __syncthreads();
    #pragma unroll
    for (int j = 0; j < 8; ++j) {
      int rl = (tid >> 5) + j * 8;
      int c4 = tid & 31;
      f32x4 v = *(const f32x4*)(smem + rl * 512 + ((c4 ^ ((rl >> 2) & 7)) << 4));
      *(f32x4*)(out + (size_t)(m0 + q * 64 + rl) * 1024 + n0 + c4 * 4) = v;
    }
    __syncthreads();
  }
}

extern "C" void kernel_launch(void* const* d_in, const int* in_sizes, int n_in,
                              void* d_out, int out_size, void* d_ws, size_t ws_size,
                              hipStream_t stream) {
  const float* x  = (const float*)d_in[0];
  const float* Wr = (const float*)d_in[1];
  const float* br = (const float*)d_in[2];
  const float* W1 = (const float*)d_in[3];
  const float* b1 = (const float*)d_in[4];
  const float* W2 = (const float*)d_in[5];
  const float* b2 = (const float*)d_in[6];
  float* out = (float*)d_out;
  unsigned char* ws  = (unsigned char*)d_ws;
  unsigned char* B1s = ws;
  unsigned char* W2s = ws + W2S_OFF;
  unsigned char* ACT = ws + ACT_OFF;

  hipLaunchKernelGGL(prep_all, dim3(424), dim3(256), 0, stream, W1, Wr, W2, b2, B1s, W2s);
  hipLaunchKernelGGL(moe_gemm1, dim3(1024), dim3(256), 0, stream, x, br, b1, B1s, ACT);
  hipLaunchKernelGGL(moe_gemm2, dim3(2048), dim3(256), 0, stream, ACT, W2s, out);
}

// Round 7
// 155.449 us; speedup vs baseline: 1.9080x; 1.2381x over previous
//
#include <hip/hip_runtime.h>

typedef float f32x4 __attribute__((ext_vector_type(4)));
typedef short bf16x8 __attribute__((ext_vector_type(8)));

// ---- workspace layout (bytes) ----
// B1s: [16 kb][528 cols][128 B]  (bf16, chunk-swizzled; cols 512-519 router, 520-527 zero)
// W2s: [1024 cols][640 B]        (bf16, chunk-swizzled; rows 256-263 = b2, 264-319 zero)
// ACT: [32768 rows][640 B]       (bf16, chunk-swizzled; k 256-263 = p, 264-319 zero)
#define B1S_KBSZ 67584
#define W2S_OFF  1081344
#define ACT_OFF  1736704
// total ws required: 22,708,224 bytes

__device__ __forceinline__ unsigned short f2bf(float f) {
  unsigned int u = __float_as_uint(f);
  return (unsigned short)((u + 0x7FFFu + ((u >> 16) & 1u)) >> 16);
}
__device__ __forceinline__ unsigned int pack2(float a, float b) {
  return (unsigned int)f2bf(a) | ((unsigned int)f2bf(b) << 16);
}
__device__ __forceinline__ unsigned int cvtpk(float a, float b) {
  unsigned int r;
  asm("v_cvt_pk_bf16_f32 %0, %1, %2" : "=v"(r) : "v"(a), "v"(b));
  return r;
}
__device__ __forceinline__ bf16x8 cvt8(f32x4 lo, f32x4 hi) {
  union { uint4 u; bf16x8 b; } r;
  r.u.x = cvtpk(lo.x, lo.y); r.u.y = cvtpk(lo.z, lo.w);
  r.u.z = cvtpk(hi.x, hi.y); r.u.w = cvtpk(hi.z, hi.w);
  return r.b;
}
__device__ __forceinline__ void async16(const void* g, void* l) {
  __builtin_amdgcn_global_load_lds(
      (const __attribute__((address_space(1))) unsigned int*)g,
      (__attribute__((address_space(3))) unsigned int*)l, 16, 0, 0);
}

// ---------------- prep: pack [W1|Wr|0] -> B1s ; [W2;b2;0] -> W2s ----------------
__global__ __launch_bounds__(256) void prep_all(const float* __restrict__ W1,
                                                const float* __restrict__ Wr,
                                                const float* __restrict__ W2,
                                                const float* __restrict__ b2,
                                                unsigned char* __restrict__ B1s,
                                                unsigned char* __restrict__ W2s) {
  if (blockIdx.x < 264) {
    int t = blockIdx.x * 256 + threadIdx.x;
    int c   = t & 7;
    int col = (t >> 3) % 528;
    int kb  = (t >> 3) / 528;
    int e   = col >> 6;
    int hh  = col & 63;
    float v[8];
    #pragma unroll
    for (int jj = 0; jj < 8; ++jj) {
      int k = kb * 64 + c * 8 + jj;
      float f;
      if (col < 512)      f = W1[(e * 1024 + k) * 64 + hh];   // W1[e][k][hh]
      else if (col < 520) f = Wr[k * 8 + (col - 512)];        // Wr[k][e]
      else                f = 0.0f;
      v[jj] = f;
    }
    *(uint4*)(B1s + kb * B1S_KBSZ + col * 128 + ((c ^ (col & 7)) * 16)) =
        make_uint4(pack2(v[0], v[1]), pack2(v[2], v[3]), pack2(v[4], v[5]), pack2(v[6], v[7]));
  } else {
    int t = (blockIdx.x - 264) * 256 + threadIdx.x;
    int cj  = t % 40;
    int col = t / 40;
    float v[8];
    #pragma unroll
    for (int jj = 0; jj < 8; ++jj) {
      int k = cj * 8 + jj;
      float f;
      if (k < 256)      f = W2[k * 1024 + col];          // W2[e][h][c], k=e*32+h
      else if (k < 264) f = b2[(k - 256) * 1024 + col];  // b2[e][c]
      else              f = 0.0f;
      v[jj] = f;
    }
    int dstc = (cj & ~7) | ((cj & 7) ^ (col & 7));
    *(uint4*)(W2s + col * 640 + dstc * 16) =
        make_uint4(pack2(v[0], v[1]), pack2(v[2], v[3]), pack2(v[4], v[5]), pack2(v[6], v[7]));
  }
}

// ---------------- kernel 1: 64x144 pair tile; A staged as f32 via async16, B dbuf ----------------
// grid 2048 = 512 M-tiles x 4 pairs; block 256 = 4 waves (2 mg x 2 ng), wave 32x80/64
__global__ __launch_bounds__(256, 2) void moe_gemm1(
    const float* __restrict__ x, const float* __restrict__ br, const float* __restrict__ b1,
    const unsigned char* __restrict__ B1s, unsigned char* __restrict__ ACT) {
  __shared__ __align__(16) unsigned char smem[69632];
  // abuf[2] @ 0 / 16384 (f32 [64 rows][256 B], chunk-swizzled key=row&7)
  // bbuf[2] @ 32768 / 51200 (bf16 [9 cf][16 r][128 B], swizzle baked in ws)
  // epilogue alias @0: hb u16[64][72] (9216) ; logit f32[64][8] @9216 ; pb u16[64][8] @11264

  const int tid  = threadIdx.x;
  const int lane = tid & 63;
  const int w    = tid >> 6;
  const int mg   = w >> 1;   // rows mg*32 .. +32
  const int ng   = w & 1;    // 0: pair frags 0-3 + router ; 1: pair frags 4-7
  const int f15  = lane & 15;
  const int fhi  = lane >> 4;
  const int k7   = f15 & 7;

  const int wid   = ((blockIdx.x & 7) << 8) + (blockIdx.x >> 3);  // XCD-chunked, 2048=8*256
  const int mtile = wid >> 2;
  const int p     = wid & 3;
  const int m0    = mtile << 6;

  f32x4 acc[2][5];
  #pragma unroll
  for (int a = 0; a < 2; ++a)
    #pragma unroll
    for (int b = 0; b < 5; ++b) acc[a][b] = f32x4{0.f, 0.f, 0.f, 0.f};

  const float* xblk = x + (size_t)m0 * 1024;

  #define STAGE1(ks, buf)                                                        \
    { unsigned char* ab_ = smem + (buf) * 16384;                                 \
      unsigned char* bb_ = smem + 32768 + (buf) * 18432;                         \
      const float* xs_ = xblk + (ks) * 64;                                       \
      _Pragma("unroll")                                                          \
      for (int i = 0; i < 4; ++i) {                                              \
        int g = i * 256 + tid;                                                   \
        int row = g >> 4, cd = g & 15;                                           \
        async16(xs_ + (size_t)row * 1024 + ((cd ^ (row & 7)) << 2), ab_ + g * 16); \
      }                                                                          \
      const unsigned char* bsrc_ = B1s + (ks) * B1S_KBSZ;                        \
      _Pragma("unroll")                                                          \
      for (int i = 0; i < 5; ++i) {                                              \
        int g = i * 256 + tid;                                                   \
        if (g < 1152) {                                                          \
          int cf = g >> 7, r = (g >> 3) & 15, c = g & 7;                         \
          int col = (cf < 8) ? (p * 128 + cf * 16 + r) : (512 + r);              \
          async16(bsrc_ + col * 128 + c * 16, bb_ + g * 16);                     \
        }                                                                        \
      } }

  STAGE1(0, 0);
  __syncthreads();

  #pragma unroll 1
  for (int ks = 0; ks < 16; ++ks) {
    const int cur = ks & 1;
    if (ks < 15) STAGE1(ks + 1, cur ^ 1);  // async loads fly under the MFMA cluster
    const unsigned char* ab = smem + cur * 16384;
    const unsigned char* bb = smem + 32768 + cur * 18432;
    #pragma unroll
    for (int ksub = 0; ksub < 2; ++ksub) {
      const int ch = ((ksub * 4 + fhi) ^ k7) << 4;
      bf16x8 af[2];
      #pragma unroll
      for (int mf = 0; mf < 2; ++mf) {
        const int row = mg * 32 + mf * 16 + f15;
        const int cx  = ksub * 8 + fhi * 2;
        f32x4 lo = *(const f32x4*)(ab + row * 256 + (((cx)     ^ k7) << 4));
        f32x4 hi = *(const f32x4*)(ab + row * 256 + (((cx + 1) ^ k7) << 4));
        af[mf] = cvt8(lo, hi);
      }
      #pragma unroll
      for (int i = 0; i < 4; ++i) {
        bf16x8 bfr = *(const bf16x8*)(bb + (ng * 4 + i) * 2048 + f15 * 128 + ch);
        acc[0][i] = __builtin_amdgcn_mfma_f32_16x16x32_bf16(af[0], bfr, acc[0][i], 0, 0, 0);
        acc[1][i] = __builtin_amdgcn_mfma_f32_16x16x32_bf16(af[1], bfr, acc[1][i], 0, 0, 0);
      }
      if (ng == 0) {
        bf16x8 bfr = *(const bf16x8*)(bb + 8 * 2048 + f15 * 128 + ch);
        acc[0][4] = __builtin_amdgcn_mfma_f32_16x16x32_bf16(af[0], bfr, acc[0][4], 0, 0, 0);
        acc[1][4] = __builtin_amdgcn_mfma_f32_16x16x32_bf16(af[1], bfr, acc[1][4], 0, 0, 0);
      }
    }
    __syncthreads();
  }

  unsigned short* hb = (unsigned short*)smem;            // [64][72] (144 B stride)
  float* logit_lds   = (float*)(smem + 9216);            // [64][8]
  unsigned short* pb = (unsigned short*)(smem + 11264);  // [64][8]

  if (ng == 0 && f15 < 8) {  // router logits + br
    float brv = br[f15];
    #pragma unroll
    for (int mf = 0; mf < 2; ++mf)
      #pragma unroll
      for (int r = 0; r < 4; ++r)
        logit_lds[(mg * 32 + mf * 16 + fhi * 4 + r) * 8 + f15] = acc[mf][4][r] + brv;
  }
  __syncthreads();

  const int e = p * 2 + ng;
  const float b1x0 = b1[e * 64 + f15],      b1x1 = b1[e * 64 + 16 + f15];
  const float b1g0 = b1[e * 64 + 32 + f15], b1g1 = b1[e * 64 + 48 + f15];

  #pragma unroll
  for (int mf = 0; mf < 2; ++mf) {
    #pragma unroll
    for (int r = 0; r < 4; ++r) {
      int row = mg * 32 + mf * 16 + fhi * 4 + r;
      const float* lg = logit_lds + row * 8;
      float l0 = lg[0], l1 = lg[1], l2 = lg[2], l3 = lg[3];
      float l4 = lg[4], l5 = lg[5], l6 = lg[6], l7 = lg[7];
      float mx = fmaxf(fmaxf(fmaxf(l0, l1), fmaxf(l2, l3)),
                       fmaxf(fmaxf(l4, l5), fmaxf(l6, l7)));
      float ssum = __expf(l0 - mx) + __expf(l1 - mx) + __expf(l2 - mx) + __expf(l3 - mx) +
                   __expf(l4 - mx) + __expf(l5 - mx) + __expf(l6 - mx) + __expf(l7 - mx);
      float rinv = 1.f / ssum;
      float pe = __expf(lg[e] - mx) * rinv;
      #pragma unroll
      for (int ci = 0; ci < 2; ++ci) {
        float xv = acc[mf][ci][r]     + (ci ? b1x1 : b1x0);
        float gv = acc[mf][ci + 2][r] + (ci ? b1g1 : b1g0);
        float av = pe * xv * gv / (1.f + __expf(-gv));  // pe * xp * silu(gate)
        hb[row * 72 + ng * 32 + ci * 16 + f15] = f2bf(av);
      }
      if (ng == 0 && f15 < 8) pb[row * 8 + f15] = f2bf(__expf(lg[f15] - mx) * rinv);
    }
  }
  __syncthreads();

  {  // ACT write: this pair's 8 chunks (+ p/zero chunks from pair 0)
    const int row = tid >> 2, q = tid & 3, key = row & 7;
    unsigned char* arow = ACT + (size_t)(m0 + row) * 640;
    #pragma unroll
    for (int j = 0; j < 2; ++j) {
      int c = q * 2 + j;  // 0..7
      uint4 v = *(const uint4*)((const unsigned char*)hb + row * 144 + c * 16);
      *(uint4*)(arow + p * 128 + ((c ^ key) << 4)) = v;
    }
    if (p == 0) {  // k 256-263 = p ; k 264-319 = 0
      #pragma unroll
      for (int j = 0; j < 2; ++j) {
        int c = q * 2 + j;
        uint4 v = make_uint4(0, 0, 0, 0);
        if (c == 0) v = *(const uint4*)((const unsigned char*)pb + row * 16);
        *(uint4*)(arow + 512 + ((c ^ key) << 4)) = v;
      }
    }
  }
}

// ---------------- kernel 2: ACT @ W2s -> out ; zero-LDS, barrier-free K-loop ----------------
// grid 2048 = 256 m x 8 n; block 256 = 4 waves (2 mg x 2 ng), wave 64x64
__global__ __launch_bounds__(256, 3) void moe_gemm2(
    const unsigned char* __restrict__ ACT, const unsigned char* __restrict__ W2s,
    float* __restrict__ out) {
  __shared__ __align__(16) unsigned char smem[32768];  // epilogue slab f32[64][128]
  const int tid  = threadIdx.x;
  const int lane = tid & 63;
  const int w    = tid >> 6;
  const int mg   = w >> 1, ng = w & 1;
  const int f15  = lane & 15, fhi = lane >> 4;
  const int k7   = f15 & 7;

  const int wid = ((blockIdx.x & 7) << 8) + (blockIdx.x >> 3);  // 2048 = 8*256
  const int m0  = (wid >> 3) * 128;
  const int n0  = (wid & 7) * 128;

  f32x4 acc[4][4];
  #pragma unroll
  for (int a = 0; a < 4; ++a)
    #pragma unroll
    for (int b = 0; b < 4; ++b) acc[a][b] = f32x4{0.f, 0.f, 0.f, 0.f};

  const unsigned char* aB = ACT + (size_t)(m0 + mg * 64 + f15) * 640;
  const unsigned char* bB = W2s + (size_t)(n0 + ng * 64 + f15) * 640;
  const int ch0 = ((fhi)     ^ k7) << 4;
  const int ch1 = ((4 + fhi) ^ k7) << 4;

  #pragma unroll
  for (int kb = 0; kb < 5; ++kb) {
    bf16x8 a0[4], a1[4];
    #pragma unroll
    for (int mf = 0; mf < 4; ++mf) {
      const unsigned char* s_ = aB + mf * 10240 + kb * 128;
      a0[mf] = *(const bf16x8*)(s_ + ch0);
      a1[mf] = *(const bf16x8*)(s_ + ch1);
    }
    #pragma unroll
    for (int nf = 0; nf < 4; ++nf) {
      const unsigned char* s_ = bB + nf * 10240 + kb * 128;
      bf16x8 b0 = *(const bf16x8*)(s_ + ch0);
      bf16x8 b1v = *(const bf16x8*)(s_ + ch1);
      #pragma unroll
      for (int mf = 0; mf < 4; ++mf)
        acc[mf][nf] = __builtin_amdgcn_mfma_f32_16x16x32_bf16(a0[mf], b0, acc[mf][nf], 0, 0, 0);
      #pragma unroll
      for (int mf = 0; mf < 4; ++mf)
        acc[mf][nf] = __builtin_amdgcn_mfma_f32_16x16x32_bf16(a1[mf], b1v, acc[mf][nf], 0, 0, 0);
    }
  }

  // epilogue: two 64-row rounds through a swizzled f32 slab -> 512B coalesced stores
  float* slab = (float*)smem;
  #pragma unroll 1
  for (int q = 0; q < 2; ++q) {
    if (mg == q) {
      #pragma unroll
      for (int mf = 0; mf < 4; ++mf)
        #pragma unroll
        for (int nf = 0; nf < 4; ++nf)
          #pragma unroll
          for (int r = 0; r < 4; ++r) {
            int rl  = mf * 16 + fhi * 4 + r;
            int col = ng * 64 + nf * 16 + f15;
            slab[rl * 128 + (col ^ (((rl >> 2) & 7) << 2))] = acc[mf][nf][r];
          }
    }
    __syncthreads();
    #pragma unroll
    for (int j = 0; j < 8; ++j) {
      int rl = (tid >> 5) + j * 8;
      int c4 = tid & 31;
      f32x4 v = *(const f32x4*)(smem + rl * 512 + ((c4 ^ ((rl >> 2) & 7)) << 4));
      *(f32x4*)(out + (size_t)(m0 + q * 64 + rl) * 1024 + n0 + c4 * 4) = v;
    }
    __syncthreads();
  }
}

extern "C" void kernel_launch(void* const* d_in, const int* in_sizes, int n_in,
                              void* d_out, int out_size, void* d_ws, size_t ws_size,
                              hipStream_t stream) {
  const float* x  = (const float*)d_in[0];
  const float* Wr = (const float*)d_in[1];
  const float* br = (const float*)d_in[2];
  const float* W1 = (const float*)d_in[3];
  const float* b1 = (const float*)d_in[4];
  const float* W2 = (const float*)d_in[5];
  const float* b2 = (const float*)d_in[6];
  float* out = (float*)d_out;
  unsigned char* ws  = (unsigned char*)d_ws;
  unsigned char* B1s = ws;
  unsigned char* W2s = ws + W2S_OFF;
  unsigned char* ACT = ws + ACT_OFF;

  hipLaunchKernelGGL(prep_all, dim3(424), dim3(256), 0, stream, W1, Wr, W2, b2, B1s, W2s);
  hipLaunchKernelGGL(moe_gemm1, dim3(2048), dim3(256), 0, stream, x, br, b1, B1s, ACT);
  hipLaunchKernelGGL(moe_gemm2, dim3(2048), dim3(256), 0, stream, ACT, W2s, out);
}